// Round 10
// baseline (1402.782 us; speedup 1.0000x reference)
//
#include <hip/hip_runtime.h>
#include <cstdint>

#define NN 50000
#define NNP 50000      // row stride of transposed buffers (multiple of 4)
#define DD 128
#define EE 600000

__device__ __forceinline__ float sigmoid_f(float x) {
    return 1.0f / (1.0f + __expf(-x));
}
__device__ __forceinline__ float tanh_f(float x) {
    float e = __expf(-2.0f * fabsf(x));
    float t = (1.0f - e) / (1.0f + e);
    return copysignf(t, x);
}

// ---- weight packing: w2[k][gate(6)][j(128)] ------------------------------
// Per (k,gate): 128 contiguous floats; a wave's 64 j-lanes load 256 B coalesced.
__global__ __launch_bounds__(256) void pack_w_kernel(const float* __restrict__ wx,
                                                     const float* __restrict__ wh,
                                                     float* __restrict__ w2) {
    int idx = blockIdx.x * 256 + threadIdx.x;
    if (idx >= 128 * 768) return;
    int k = idx / 768;
    int rem = idx - k * 768;
    int g = rem >> 7;
    int j = rem & 127;
    float v = (g < 3) ? wx[(g * 128 + j) * 128 + k]
                      : wh[((g - 3) * 128 + j) * 128 + k];
    w2[idx] = v;
}

// ---- CSR build (all 4 adjacencies batched) -------------------------------

__global__ __launch_bounds__(256) void hist_kernel(const int* __restrict__ rows,
                                                   int* __restrict__ cnt4) {
    int e = blockIdx.x * 256 + threadIdx.x;
    if (e >= EE) return;
    int k = blockIdx.y;
    atomicAdd(&cnt4[k * NN + rows[(size_t)k * EE + e]], 1);
}

__global__ __launch_bounds__(1024) void scan_kernel(const int* __restrict__ cnt4,
                                                    int* __restrict__ row_ptr4,
                                                    int* __restrict__ cursor4) {
    __shared__ int buf[1024];
    const int kadj = blockIdx.x;
    const int* cnt = cnt4 + kadj * NN;
    int* row_ptr = row_ptr4 + kadj * (NN + 1);
    int* cursor = cursor4 + kadj * NN;
    const int tid = threadIdx.x;
    const int CH = (NN + 1023) / 1024;  // 49
    const int base = tid * CH;
    int s = 0;
    #pragma unroll
    for (int i = 0; i < CH; ++i) {
        int idx = base + i;
        if (idx < NN) s += cnt[idx];
    }
    buf[tid] = s;
    __syncthreads();
    for (int d = 1; d < 1024; d <<= 1) {
        int t = (tid >= d) ? buf[tid - d] : 0;
        __syncthreads();
        buf[tid] += t;
        __syncthreads();
    }
    int run = buf[tid] - s;
    #pragma unroll
    for (int i = 0; i < CH; ++i) {
        int idx = base + i;
        if (idx < NN) {
            row_ptr[idx] = run;
            cursor[idx] = run;
            run += cnt[idx];
        }
    }
    if (tid == 0) row_ptr[NN] = EE;
}

__global__ __launch_bounds__(256) void scatter_kernel(const int* __restrict__ rows,
                                                      const int* __restrict__ cols,
                                                      const float* __restrict__ vals,
                                                      int* __restrict__ cursor4,
                                                      int2* __restrict__ epair4) {
    int e = blockIdx.x * 256 + threadIdx.x;
    if (e >= EE) return;
    int k = blockIdx.y;
    size_t off = (size_t)k * EE + e;
    int r = rows[off];
    int pos = atomicAdd(&cursor4[k * NN + r], 1);
    int2 p;
    p.x = cols[off];
    p.y = __float_as_int(vals[off]);
    epair4[(size_t)k * EE + pos] = p;
}

// ---- SpMM gather -> TRANSPOSED output: resT[k][row] = relu(sum val*x[col])
// half-wave (32 lanes) per row, 8 rows/block; LDS tile re-lays [8][128]->[128][8]
__global__ __launch_bounds__(256) void gather_kernel(const float* __restrict__ x,
                                                     const int* __restrict__ row_ptr,
                                                     const int2* __restrict__ epair,
                                                     float* __restrict__ resT) {
    __shared__ float s_t[128 * 9];     // [d][8 rows], pad 9 vs 8
    const int tid = threadIdx.x;
    const int rl = tid >> 5;
    const int row0 = blockIdx.x * 8;
    const int row = row0 + rl;
    const int d0 = (tid & 31) * 4;
    const int start = row_ptr[row];
    const int end = row_ptr[row + 1];
    float4 a0 = make_float4(0.f, 0.f, 0.f, 0.f);
    float4 a1 = a0, a2 = a0, a3 = a0;
    int e = start;
    for (; e + 3 < end; e += 4) {
        int2 p0 = epair[e], p1 = epair[e + 1], p2 = epair[e + 2], p3 = epair[e + 3];
        float4 x0 = *reinterpret_cast<const float4*>(x + (size_t)p0.x * DD + d0);
        float4 x1 = *reinterpret_cast<const float4*>(x + (size_t)p1.x * DD + d0);
        float4 x2 = *reinterpret_cast<const float4*>(x + (size_t)p2.x * DD + d0);
        float4 x3 = *reinterpret_cast<const float4*>(x + (size_t)p3.x * DD + d0);
        float v0 = __int_as_float(p0.y), v1 = __int_as_float(p1.y);
        float v2 = __int_as_float(p2.y), v3 = __int_as_float(p3.y);
        a0.x += v0 * x0.x; a0.y += v0 * x0.y; a0.z += v0 * x0.z; a0.w += v0 * x0.w;
        a1.x += v1 * x1.x; a1.y += v1 * x1.y; a1.z += v1 * x1.z; a1.w += v1 * x1.w;
        a2.x += v2 * x2.x; a2.y += v2 * x2.y; a2.z += v2 * x2.z; a2.w += v2 * x2.w;
        a3.x += v3 * x3.x; a3.y += v3 * x3.y; a3.z += v3 * x3.z; a3.w += v3 * x3.w;
    }
    for (; e < end; ++e) {
        int2 p0 = epair[e];
        float v0 = __int_as_float(p0.y);
        float4 x0 = *reinterpret_cast<const float4*>(x + (size_t)p0.x * DD + d0);
        a0.x += v0 * x0.x; a0.y += v0 * x0.y; a0.z += v0 * x0.z; a0.w += v0 * x0.w;
    }
    float o[4];
    o[0] = fmaxf((a0.x + a1.x) + (a2.x + a3.x), 0.f);
    o[1] = fmaxf((a0.y + a1.y) + (a2.y + a3.y), 0.f);
    o[2] = fmaxf((a0.z + a1.z) + (a2.z + a3.z), 0.f);
    o[3] = fmaxf((a0.w + a1.w) + (a2.w + a3.w), 0.f);
    #pragma unroll
    for (int i = 0; i < 4; ++i) s_t[(d0 + i) * 9 + rl] = o[i];
    __syncthreads();
    int d = tid >> 1;
    int rh = (tid & 1) * 4;
    const float* sp = &s_t[d * 9 + rh];
    float4 v = make_float4(sp[0], sp[1], sp[2], sp[3]);
    *reinterpret_cast<float4*>(resT + (size_t)d * NNP + row0 + rh) = v;
}

// ---- Fused dual-GEMM + GRU, j-per-lane, no LDS ---------------------------
// 512 threads = 8 waves = 2 j-halves x 4 row-subsets x 4 rows; 3125 blocks.
// Inputs (resT/hT, [k][row]) are wave-uniform -> scalar loads (lgkm only,
// chunked 4-k). Weights (w2[k][gate][j]) are lane-varying -> vector loads
// (vmcnt pipe, 256B coalesced). acc in 16 VGPR; target 8 waves/SIMD.
template <bool FIRST, bool LAST>
__global__ __launch_bounds__(512, 8)
void gru_step_kernel(const float* __restrict__ resT,
                     const float* __restrict__ hT_in,
                     float* __restrict__ hT_out,
                     float* __restrict__ h_last,
                     const float* __restrict__ w2,
                     const float* __restrict__ bx,
                     const float* __restrict__ bh) {
    const int tid = threadIdx.x;
    const int lane = tid & 63;
    const int wave = __builtin_amdgcn_readfirstlane(tid >> 6);  // 0..7, uniform
    const int j = (wave & 1) * 64 + lane;
    const int row0 = blockIdx.x * 16 + (wave >> 1) * 4;

    const float* aT = resT + row0;
    const float* bT = hT_in + row0;
    const float* wb = w2 + j;                    // lane-varying base

    float sr[4], si[4], sn[4], hn[4];
    {
        float bxr = bx[j], bxi = bx[DD + j], bxn = bx[2 * DD + j];
        float bhr = bh[j], bhi = bh[DD + j], bhn = bh[2 * DD + j];
        #pragma unroll
        for (int r = 0; r < 4; ++r) {
            sr[r] = bxr + bhr;
            si[r] = bxi + bhi;
            sn[r] = bxn;
            hn[r] = bhn;
        }
    }

    float4 ho = make_float4(0.f, 0.f, 0.f, 0.f);
    if (!FIRST)
        ho = *reinterpret_cast<const float4*>(hT_in + (size_t)j * NNP + row0);

    for (int kc = 0; kc < DD; kc += 4) {
        float4 a[4], b[4];
        #pragma unroll
        for (int i = 0; i < 4; ++i) {
            a[i] = *reinterpret_cast<const float4*>(aT + (size_t)(kc + i) * NNP);
            if (!FIRST)
                b[i] = *reinterpret_cast<const float4*>(bT + (size_t)(kc + i) * NNP);
        }
        #pragma unroll
        for (int i = 0; i < 4; ++i) {
            const float* wk = wb + (size_t)(kc + i) * 768;
            float wr = wk[0], wi = wk[128], wn = wk[256];
            float vr = 0.f, vi = 0.f, vn = 0.f;
            if (!FIRST) { vr = wk[384]; vi = wk[512]; vn = wk[640]; }
            float av[4] = {a[i].x, a[i].y, a[i].z, a[i].w};
            float bv[4] = {b[i].x, b[i].y, b[i].z, b[i].w};
            #pragma unroll
            for (int r = 0; r < 4; ++r) {
                sr[r] += av[r] * wr;
                si[r] += av[r] * wi;
                sn[r] += av[r] * wn;
                if (!FIRST) {
                    sr[r] += bv[r] * vr;
                    si[r] += bv[r] * vi;
                    hn[r] += bv[r] * vn;
                }
            }
        }
    }

    float o[4];
    float hov[4] = {ho.x, ho.y, ho.z, ho.w};
    #pragma unroll
    for (int r = 0; r < 4; ++r) {
        float rg = sigmoid_f(sr[r]);
        float ig = sigmoid_f(si[r]);
        float ng = tanh_f(sn[r] + rg * hn[r]);
        o[r] = ng + ig * (hov[r] - ng);
    }

    if (!LAST) {
        *reinterpret_cast<float4*>(hT_out + (size_t)j * NNP + row0) =
            make_float4(o[0], o[1], o[2], o[3]);
    } else {
        #pragma unroll
        for (int r = 0; r < 4; ++r)
            h_last[(size_t)(row0 + r) * DD + j] = o[r];
    }
}

// LayerNorm over D=128, 32 lanes/row, two-pass variance (matches jnp.var)
__global__ __launch_bounds__(256) void ln_kernel(float* __restrict__ h,
                                                 const float* __restrict__ g,
                                                 const float* __restrict__ b) {
    int tid = threadIdx.x;
    int lane = tid & 31;
    int rl = tid >> 5;
    int row = blockIdx.x * 8 + rl;
    if (row >= NN) return;
    float4 v = *reinterpret_cast<const float4*>(h + (size_t)row * DD + lane * 4);
    float s = v.x + v.y + v.z + v.w;
    #pragma unroll
    for (int m = 16; m >= 1; m >>= 1) s += __shfl_xor(s, m, 64);
    float mean = s * (1.0f / DD);
    float dx = v.x - mean, dy = v.y - mean, dz = v.z - mean, dw = v.w - mean;
    float q = dx * dx + dy * dy + dz * dz + dw * dw;
    #pragma unroll
    for (int m = 16; m >= 1; m >>= 1) q += __shfl_xor(q, m, 64);
    float var = q * (1.0f / DD);
    float inv = 1.0f / sqrtf(var + 1e-5f);
    float4 gv = *reinterpret_cast<const float4*>(g + lane * 4);
    float4 bv = *reinterpret_cast<const float4*>(b + lane * 4);
    float4 o;
    o.x = dx * inv * gv.x + bv.x;
    o.y = dy * inv * gv.y + bv.y;
    o.z = dz * inv * gv.z + bv.z;
    o.w = dw * inv * gv.w + bv.w;
    *reinterpret_cast<float4*>(h + (size_t)row * DD + lane * 4) = o;
}

static inline size_t align_up(size_t v, size_t a) { return (v + a - 1) & ~(a - 1); }

extern "C" void kernel_launch(void* const* d_in, const int* in_sizes, int n_in,
                              void* d_out, int out_size, void* d_ws, size_t ws_size,
                              hipStream_t stream) {
    const float* x    = (const float*)d_in[0];
    const float* vals = (const float*)d_in[1];
    const float* wx   = (const float*)d_in[2];
    const float* bx   = (const float*)d_in[3];
    const float* wh   = (const float*)d_in[4];
    const float* bh   = (const float*)d_in[5];
    const float* lng  = (const float*)d_in[6];
    const float* lnb  = (const float*)d_in[7];
    const int* rows   = (const int*)d_in[8];
    const int* cols   = (const int*)d_in[9];

    float* hout = (float*)d_out;

    size_t off = 0;
    char* wsb = (char*)d_ws;
    float* resT = (float*)(wsb + off);     off = align_up(off + (size_t)DD * NNP * 4, 256);
    float* hT0 = (float*)(wsb + off);      off = align_up(off + (size_t)DD * NNP * 4, 256);
    float* hT1 = (float*)(wsb + off);      off = align_up(off + (size_t)DD * NNP * 4, 256);
    float* w2 = (float*)(wsb + off);       off = align_up(off + (size_t)128 * 768 * 4, 256);
    int* row_ptr4 = (int*)(wsb + off);     off = align_up(off + (size_t)4 * (NN + 1) * 4, 256);
    int* cnt4 = (int*)(wsb + off);         off = align_up(off + (size_t)4 * NN * 4, 256);
    int* cursor4 = (int*)(wsb + off);      off = align_up(off + (size_t)4 * NN * 4, 256);
    int2* epair4 = (int2*)(wsb + off);     off = align_up(off + (size_t)4 * EE * 8, 256);

    (void)in_sizes; (void)n_in; (void)out_size; (void)ws_size;

    pack_w_kernel<<<384, 256, 0, stream>>>(wx, wh, w2);

    hipMemsetAsync(cnt4, 0, (size_t)4 * NN * sizeof(int), stream);
    dim3 egrid((EE + 255) / 256, 4);
    hist_kernel<<<egrid, 256, 0, stream>>>(rows, cnt4);
    scan_kernel<<<4, 1024, 0, stream>>>(cnt4, row_ptr4, cursor4);
    scatter_kernel<<<egrid, 256, 0, stream>>>(rows, cols, vals, cursor4, epair4);

    const int ggrid = NN / 8;              // 6250
    const int grug = NN / 16;              // 3125 (exact)

    // hT ping-pong: s0 -> hT0, s1 hT0->hT1, s2 hT1->hT0, s3 hT0 -> d_out (normal)
    for (int s = 0; s < 4; ++s) {
        int k = 3 - s;  // adj_list reversed
        gather_kernel<<<ggrid, 256, 0, stream>>>(
            x, row_ptr4 + (size_t)k * (NN + 1), epair4 + (size_t)k * EE, resT);
        if (s == 0)
            gru_step_kernel<true, false><<<grug, 512, 0, stream>>>(
                resT, nullptr, hT0, nullptr, w2, bx, bh);
        else if (s == 1)
            gru_step_kernel<false, false><<<grug, 512, 0, stream>>>(
                resT, hT0, hT1, nullptr, w2, bx, bh);
        else if (s == 2)
            gru_step_kernel<false, false><<<grug, 512, 0, stream>>>(
                resT, hT1, hT0, nullptr, w2, bx, bh);
        else
            gru_step_kernel<false, true><<<grug, 512, 0, stream>>>(
                resT, hT0, nullptr, hout, w2, bx, bh);
    }

    ln_kernel<<<(NN + 7) / 8, 256, 0, stream>>>(hout, lng, lnb);
}

// Round 11
// 868.000 us; speedup vs baseline: 1.6161x; 1.6161x over previous
//
#include <hip/hip_runtime.h>
#include <cstdint>

#define NN 50000
#define DD 128
#define EE 600000

typedef __attribute__((ext_vector_type(8))) short bf16x8;
typedef __attribute__((ext_vector_type(4))) float f32x4;

__device__ __forceinline__ float sigmoid_f(float x) {
    return 1.0f / (1.0f + __expf(-x));
}
__device__ __forceinline__ float tanh_f(float x) {
    float e = __expf(-2.0f * fabsf(x));
    float t = (1.0f - e) / (1.0f + e);
    return copysignf(t, x);
}
__device__ __forceinline__ unsigned short bf16_rn(float v) {
    unsigned u = __float_as_uint(v);
    u = u + 0x7fffu + ((u >> 16) & 1u);
    return (unsigned short)(u >> 16);
}
__device__ __forceinline__ float bf16_tf(unsigned short h) {
    return __uint_as_float(((unsigned)h) << 16);
}

// ---- weight packing into MFMA B-panels -----------------------------------
// Wp[kb(24)][n(512)][k8(32)] bf16. K-groups (A-side pairing):
//  grp 0: Rh*Wx_hi  1: Rl*Wx_hi  2: Rh*Wx_lo  3: Hh*Wh_hi  4: Hl*Wh_hi  5: Hh*Wh_lo
// n cols: [r(0:128) | i(128:256) | i_n(256:384) | h_n(384:512)], zero-padded.
__global__ __launch_bounds__(256) void pack_w_kernel(const float* __restrict__ wx,
                                                     const float* __restrict__ wh,
                                                     unsigned short* __restrict__ Wp) {
    int idx = blockIdx.x * 256 + threadIdx.x;   // 24*512*32
    if (idx >= 24 * 512 * 32) return;
    int k8 = idx & 31;
    int n = (idx >> 5) & 511;
    int kb = idx >> 14;
    int grp = kb >> 2;
    int k = (kb & 3) * 32 + k8;
    float v = 0.f;
    if (grp < 3) {
        if (n < 384) v = wx[n * 128 + k];
    } else {
        if (n < 256) v = wh[n * 128 + k];
        else if (n >= 384) v = wh[(n - 128) * 128 + k];
    }
    unsigned short hi = bf16_rn(v);
    bool lo = (grp == 2) || (grp == 5);
    Wp[idx] = lo ? bf16_rn(v - bf16_tf(hi)) : hi;
}

// ---- CSR build (all 4 adjacencies batched) -------------------------------

__global__ __launch_bounds__(256) void hist_kernel(const int* __restrict__ rows,
                                                   int* __restrict__ cnt4) {
    int e = blockIdx.x * 256 + threadIdx.x;
    if (e >= EE) return;
    int k = blockIdx.y;
    atomicAdd(&cnt4[k * NN + rows[(size_t)k * EE + e]], 1);
}

__global__ __launch_bounds__(1024) void scan_kernel(const int* __restrict__ cnt4,
                                                    int* __restrict__ row_ptr4,
                                                    int* __restrict__ cursor4) {
    __shared__ int buf[1024];
    const int kadj = blockIdx.x;
    const int* cnt = cnt4 + kadj * NN;
    int* row_ptr = row_ptr4 + kadj * (NN + 1);
    int* cursor = cursor4 + kadj * NN;
    const int tid = threadIdx.x;
    const int CH = (NN + 1023) / 1024;  // 49
    const int base = tid * CH;
    int s = 0;
    #pragma unroll
    for (int i = 0; i < CH; ++i) {
        int idx = base + i;
        if (idx < NN) s += cnt[idx];
    }
    buf[tid] = s;
    __syncthreads();
    for (int d = 1; d < 1024; d <<= 1) {
        int t = (tid >= d) ? buf[tid - d] : 0;
        __syncthreads();
        buf[tid] += t;
        __syncthreads();
    }
    int run = buf[tid] - s;
    #pragma unroll
    for (int i = 0; i < CH; ++i) {
        int idx = base + i;
        if (idx < NN) {
            row_ptr[idx] = run;
            cursor[idx] = run;
            run += cnt[idx];
        }
    }
    if (tid == 0) row_ptr[NN] = EE;
}

__global__ __launch_bounds__(256) void scatter_kernel(const int* __restrict__ rows,
                                                      const int* __restrict__ cols,
                                                      const float* __restrict__ vals,
                                                      int* __restrict__ cursor4,
                                                      int2* __restrict__ epair4) {
    int e = blockIdx.x * 256 + threadIdx.x;
    if (e >= EE) return;
    int k = blockIdx.y;
    size_t off = (size_t)k * EE + e;
    int r = rows[off];
    int pos = atomicAdd(&cursor4[k * NN + r], 1);
    int2 p;
    p.x = cols[off];
    p.y = __float_as_int(vals[off]);
    epair4[(size_t)k * EE + pos] = p;
}

// ---- SpMM gather: Rh/Rl = split-bf16(relu(sum val*x[col])) ---------------
__global__ __launch_bounds__(256) void gather_kernel(const float* __restrict__ x,
                                                     const int* __restrict__ row_ptr,
                                                     const int2* __restrict__ epair,
                                                     unsigned short* __restrict__ Rh,
                                                     unsigned short* __restrict__ Rl) {
    const int tid = threadIdx.x;
    const int row = blockIdx.x * 8 + (tid >> 5);
    const int d0 = (tid & 31) * 4;
    const int start = row_ptr[row];
    const int end = row_ptr[row + 1];
    float4 a0 = make_float4(0.f, 0.f, 0.f, 0.f);
    float4 a1 = a0, a2 = a0, a3 = a0;
    int e = start;
    for (; e + 3 < end; e += 4) {
        int2 p0 = epair[e], p1 = epair[e + 1], p2 = epair[e + 2], p3 = epair[e + 3];
        float4 x0 = *reinterpret_cast<const float4*>(x + (size_t)p0.x * DD + d0);
        float4 x1 = *reinterpret_cast<const float4*>(x + (size_t)p1.x * DD + d0);
        float4 x2 = *reinterpret_cast<const float4*>(x + (size_t)p2.x * DD + d0);
        float4 x3 = *reinterpret_cast<const float4*>(x + (size_t)p3.x * DD + d0);
        float v0 = __int_as_float(p0.y), v1 = __int_as_float(p1.y);
        float v2 = __int_as_float(p2.y), v3 = __int_as_float(p3.y);
        a0.x += v0 * x0.x; a0.y += v0 * x0.y; a0.z += v0 * x0.z; a0.w += v0 * x0.w;
        a1.x += v1 * x1.x; a1.y += v1 * x1.y; a1.z += v1 * x1.z; a1.w += v1 * x1.w;
        a2.x += v2 * x2.x; a2.y += v2 * x2.y; a2.z += v2 * x2.z; a2.w += v2 * x2.w;
        a3.x += v3 * x3.x; a3.y += v3 * x3.y; a3.z += v3 * x3.z; a3.w += v3 * x3.w;
    }
    for (; e < end; ++e) {
        int2 p0 = epair[e];
        float v0 = __int_as_float(p0.y);
        float4 x0 = *reinterpret_cast<const float4*>(x + (size_t)p0.x * DD + d0);
        a0.x += v0 * x0.x; a0.y += v0 * x0.y; a0.z += v0 * x0.z; a0.w += v0 * x0.w;
    }
    float o[4];
    o[0] = fmaxf((a0.x + a1.x) + (a2.x + a3.x), 0.f);
    o[1] = fmaxf((a0.y + a1.y) + (a2.y + a3.y), 0.f);
    o[2] = fmaxf((a0.z + a1.z) + (a2.z + a3.z), 0.f);
    o[3] = fmaxf((a0.w + a1.w) + (a2.w + a3.w), 0.f);
    ushort4 vh, vl;
    unsigned short h0 = bf16_rn(o[0]); vh.x = h0; vl.x = bf16_rn(o[0] - bf16_tf(h0));
    unsigned short h1 = bf16_rn(o[1]); vh.y = h1; vl.y = bf16_rn(o[1] - bf16_tf(h1));
    unsigned short h2 = bf16_rn(o[2]); vh.z = h2; vl.z = bf16_rn(o[2] - bf16_tf(h2));
    unsigned short h3 = bf16_rn(o[3]); vh.w = h3; vl.w = bf16_rn(o[3] - bf16_tf(h3));
    *reinterpret_cast<ushort4*>(Rh + (size_t)row * DD + d0) = vh;
    *reinterpret_cast<ushort4*>(Rl + (size_t)row * DD + d0) = vl;
}

// ---- MFMA split-bf16 dual-GEMM + fused GRU -------------------------------
// Block: 64 rows x 512 out-cols, 256 thr = 4 waves; wave w owns j in
// [w*32,(w+1)*32) across ALL 4 gate blocks (epilogue self-contained).
// A (Rh/Rl/Hh/Hl slabs) staged once in LDS, XOR-swizzled; ONE barrier; 24
// k-block loop reads B from packed global panel (L2-resident).
template <bool FIRST, bool LAST>
__global__ __launch_bounds__(256, 2)
void gemm_gru_kernel(const unsigned short* __restrict__ Rh,
                     const unsigned short* __restrict__ Rl,
                     unsigned short* __restrict__ Hh,
                     unsigned short* __restrict__ Hl,
                     float* __restrict__ hbuf,
                     float* __restrict__ hout,
                     const unsigned short* __restrict__ Wp,
                     const float* __restrict__ bx,
                     const float* __restrict__ bh) {
    constexpr int NARR = FIRST ? 2 : 4;
    constexpr int NG = FIRST ? 3 : 4;
    constexpr int KB = FIRST ? 12 : 24;
    __shared__ unsigned short sA[NARR * 64 * 128];   // 32/64 KB

    const int tid = threadIdx.x;
    const int row0 = blockIdx.x * 64;

    // stage A slabs: unit = (arr, row, slot16B); swizzle slot ^= row&7
    {
        const unsigned short* srcs[4] = {Rh, Rl, Hh, Hl};
        #pragma unroll
        for (int it = 0; it < NARR * 4; ++it) {
            int arr = it >> 2;                         // compile-time per it
            int row = ((it & 3) * 256 + tid) >> 4;     // 0..63
            int slot = tid & 15;
            int grow = row0 + row;
            uint4 v = make_uint4(0, 0, 0, 0);
            if (grow < NN)
                v = *reinterpret_cast<const uint4*>(srcs[arr] + (size_t)grow * 128 + slot * 8);
            int sw = slot ^ (row & 7);
            *reinterpret_cast<uint4*>(sA + ((arr * 64 + row) * 16 + sw) * 8) = v;
        }
    }
    __syncthreads();

    const int lane = tid & 63;
    const int w = tid >> 6;        // wave 0..3
    const int g = lane >> 4;       // 0..3
    const int m16 = lane & 15;

    f32x4 acc[4][2][4];            // [gate][jt][mt]
    #pragma unroll
    for (int G = 0; G < 4; ++G)
        #pragma unroll
        for (int jt = 0; jt < 2; ++jt)
            #pragma unroll
            for (int mt = 0; mt < 4; ++mt)
                acc[G][jt][mt] = (f32x4){0.f, 0.f, 0.f, 0.f};

    for (int kb = 0; kb < KB; ++kb) {
        int grp = kb >> 2;
        int arr = (0x232010 >> (grp * 4)) & 15;   // {0,1,0,2,3,2}[grp]
        int kq = kb & 3;

        bf16x8 bfr[4][2];
        #pragma unroll
        for (int G = 0; G < NG; ++G)
            #pragma unroll
            for (int jt = 0; jt < 2; ++jt) {
                int n = G * 128 + w * 32 + jt * 16 + m16;
                bfr[G][jt] = *reinterpret_cast<const bf16x8*>(
                    Wp + ((size_t)(kb * 512 + n)) * 32 + g * 8);
            }
        bf16x8 afr[4];
        #pragma unroll
        for (int mt = 0; mt < 4; ++mt) {
            int row = mt * 16 + m16;
            int sw = (kq * 4 + g) ^ (row & 7);
            afr[mt] = *reinterpret_cast<const bf16x8*>(
                sA + ((arr * 64 + row) * 16 + sw) * 8);
        }
        #pragma unroll
        for (int mt = 0; mt < 4; ++mt)
            #pragma unroll
            for (int G = 0; G < NG; ++G)
                #pragma unroll
                for (int jt = 0; jt < 2; ++jt)
                    acc[G][jt][mt] = __builtin_amdgcn_mfma_f32_16x16x32_bf16(
                        afr[mt], bfr[G][jt], acc[G][jt][mt], 0, 0, 0);
    }

    // GRU epilogue: C layout col=lane&15, row=(lane>>4)*4+ii (verified m89)
    #pragma unroll
    for (int jt = 0; jt < 2; ++jt) {
        int j = w * 32 + jt * 16 + m16;
        float bxr = bx[j], bxi = bx[128 + j], bxn = bx[256 + j];
        float bhr = bh[j], bhi = bh[128 + j], bhn = bh[256 + j];
        #pragma unroll
        for (int mt = 0; mt < 4; ++mt) {
            int rbase = row0 + mt * 16 + g * 4;
            #pragma unroll
            for (int ii = 0; ii < 4; ++ii) {
                int grow = rbase + ii;
                if (grow >= NN) continue;
                float rr = acc[0][jt][mt][ii] + bxr + bhr;
                float ri = acc[1][jt][mt][ii] + bxi + bhi;
                float rin = acc[2][jt][mt][ii] + bxn;
                float rhn = bhn;
                if (!FIRST) rhn += acc[3][jt][mt][ii];
                float rg = sigmoid_f(rr);
                float ig = sigmoid_f(ri);
                float ng = tanh_f(rin + rg * rhn);
                float ho = 0.f;
                if (!FIRST) ho = hbuf[(size_t)grow * 128 + j];
                float hy = ng + ig * (ho - ng);
                if (LAST) {
                    hout[(size_t)grow * 128 + j] = hy;
                } else {
                    hbuf[(size_t)grow * 128 + j] = hy;
                    unsigned short hh = bf16_rn(hy);
                    Hh[(size_t)grow * 128 + j] = hh;
                    Hl[(size_t)grow * 128 + j] = bf16_rn(hy - bf16_tf(hh));
                }
            }
        }
    }
}

// LayerNorm over D=128, 32 lanes/row, two-pass variance (matches jnp.var)
__global__ __launch_bounds__(256) void ln_kernel(float* __restrict__ h,
                                                 const float* __restrict__ g,
                                                 const float* __restrict__ b) {
    int tid = threadIdx.x;
    int lane = tid & 31;
    int rl = tid >> 5;
    int row = blockIdx.x * 8 + rl;
    if (row >= NN) return;
    float4 v = *reinterpret_cast<const float4*>(h + (size_t)row * DD + lane * 4);
    float s = v.x + v.y + v.z + v.w;
    #pragma unroll
    for (int m = 16; m >= 1; m >>= 1) s += __shfl_xor(s, m, 64);
    float mean = s * (1.0f / DD);
    float dx = v.x - mean, dy = v.y - mean, dz = v.z - mean, dw = v.w - mean;
    float q = dx * dx + dy * dy + dz * dz + dw * dw;
    #pragma unroll
    for (int m = 16; m >= 1; m >>= 1) q += __shfl_xor(q, m, 64);
    float var = q * (1.0f / DD);
    float inv = 1.0f / sqrtf(var + 1e-5f);
    float4 gv = *reinterpret_cast<const float4*>(g + lane * 4);
    float4 bv = *reinterpret_cast<const float4*>(b + lane * 4);
    float4 o;
    o.x = dx * inv * gv.x + bv.x;
    o.y = dy * inv * gv.y + bv.y;
    o.z = dz * inv * gv.z + bv.z;
    o.w = dw * inv * gv.w + bv.w;
    *reinterpret_cast<float4*>(h + (size_t)row * DD + lane * 4) = o;
}

static inline size_t align_up(size_t v, size_t a) { return (v + a - 1) & ~(a - 1); }

extern "C" void kernel_launch(void* const* d_in, const int* in_sizes, int n_in,
                              void* d_out, int out_size, void* d_ws, size_t ws_size,
                              hipStream_t stream) {
    const float* x    = (const float*)d_in[0];
    const float* vals = (const float*)d_in[1];
    const float* wx   = (const float*)d_in[2];
    const float* bx   = (const float*)d_in[3];
    const float* wh   = (const float*)d_in[4];
    const float* bh   = (const float*)d_in[5];
    const float* lng  = (const float*)d_in[6];
    const float* lnb  = (const float*)d_in[7];
    const int* rows   = (const int*)d_in[8];
    const int* cols   = (const int*)d_in[9];

    float* hout = (float*)d_out;

    size_t off = 0;
    char* wsb = (char*)d_ws;
    unsigned short* Rh = (unsigned short*)(wsb + off); off = align_up(off + (size_t)NN * DD * 2, 256);
    unsigned short* Rl = (unsigned short*)(wsb + off); off = align_up(off + (size_t)NN * DD * 2, 256);
    unsigned short* Hh = (unsigned short*)(wsb + off); off = align_up(off + (size_t)NN * DD * 2, 256);
    unsigned short* Hl = (unsigned short*)(wsb + off); off = align_up(off + (size_t)NN * DD * 2, 256);
    float* hbuf = (float*)(wsb + off);                 off = align_up(off + (size_t)NN * DD * 4, 256);
    unsigned short* Wp = (unsigned short*)(wsb + off); off = align_up(off + (size_t)24 * 512 * 32 * 2, 256);
    int* row_ptr4 = (int*)(wsb + off);  off = align_up(off + (size_t)4 * (NN + 1) * 4, 256);
    int* cnt4 = (int*)(wsb + off);      off = align_up(off + (size_t)4 * NN * 4, 256);
    int* cursor4 = (int*)(wsb + off);   off = align_up(off + (size_t)4 * NN * 4, 256);
    int2* epair4 = (int2*)(wsb + off);  off = align_up(off + (size_t)4 * EE * 8, 256);

    (void)in_sizes; (void)n_in; (void)out_size; (void)ws_size;

    pack_w_kernel<<<1536, 256, 0, stream>>>(wx, wh, Wp);

    hipMemsetAsync(cnt4, 0, (size_t)4 * NN * sizeof(int), stream);
    dim3 egrid((EE + 255) / 256, 4);
    hist_kernel<<<egrid, 256, 0, stream>>>(rows, cnt4);
    scan_kernel<<<4, 1024, 0, stream>>>(cnt4, row_ptr4, cursor4);
    scatter_kernel<<<egrid, 256, 0, stream>>>(rows, cols, vals, cursor4, epair4);

    const int ggrid = NN / 8;                 // 6250
    const int mgrid = (NN + 63) / 64;         // 782

    for (int s = 0; s < 4; ++s) {
        int k = 3 - s;  // adj_list reversed
        gather_kernel<<<ggrid, 256, 0, stream>>>(
            x, row_ptr4 + (size_t)k * (NN + 1), epair4 + (size_t)k * EE, Rh, Rl);
        if (s == 0)
            gemm_gru_kernel<true, false><<<mgrid, 256, 0, stream>>>(
                Rh, Rl, Hh, Hl, hbuf, nullptr, Wp, bx, bh);
        else if (s < 3)
            gemm_gru_kernel<false, false><<<mgrid, 256, 0, stream>>>(
                Rh, Rl, Hh, Hl, hbuf, nullptr, Wp, bx, bh);
        else
            gemm_gru_kernel<false, true><<<mgrid, 256, 0, stream>>>(
                Rh, Rl, Hh, Hl, hbuf, hout, Wp, bx, bh);
    }

    ln_kernel<<<(NN + 7) / 8, 256, 0, stream>>>(hout, lng, lnb);
}